// Round 1
// baseline (366.609 us; speedup 1.0000x reference)
//
#include <hip/hip_runtime.h>
#include <math.h>

// Problem constants (fixed by setup_inputs): bs=128, seq=4096, hidden=128, fp32.
#define B_ 128
#define S_ 4096
#define H_ 128
#define SPLITS_ 8                 // seq splits per batch -> 1024 blocks in pass1
#define CHUNK_ (S_ / SPLITS_)     // 512 positions per block
#define NPART_ (H_ + 2)           // per-partial: {m, l, ctx[128]}

// ---------------- Pass 1: streamed scores + online-softmax context partials ----
// Block = (batch b, split). 256 threads = 4 waves. Each wave-iteration loads
// 2 positions (float4/lane = 1 KiB/wave): lanes 0-31 -> position sl, lanes
// 32-63 -> position sl+1. Score reduced inside each 32-lane half via
// __shfl_xor 1/2/4/8/16 (xor<32 never crosses the half boundary). Each half
// keeps its own online-softmax state (m, l, ctx4); halves merge at xor-32,
// waves merge via LDS. Raw scores stored to the attn output region (2 MiB),
// normalized later by pass 2.
__global__ __launch_bounds__(256) void s2s_attn_pass1(
    const float* __restrict__ dec, const float* __restrict__ enc,
    float* __restrict__ score_out, float* __restrict__ part_out) {
  const int blk = blockIdx.x;
  const int b = blk / SPLITS_;
  const int split = blk - b * SPLITS_;
  const int t = threadIdx.x;
  const int w = t >> 6;        // wave 0..3
  const int lane = t & 63;
  const int half = lane >> 5;  // which position of the pair
  const int l32 = lane & 31;   // h-slice owner: h = l32*4 .. +3

  __shared__ float s_score[CHUNK_];   // 2 KiB raw scores for coalesced write-out
  __shared__ float s_m[4];
  __shared__ float s_l[4];
  __shared__ float s_ctx[4][H_];      // 2 KiB per-wave context partials

  const float4 dv = *reinterpret_cast<const float4*>(dec + b * H_ + l32 * 4);
  const float* encb = enc + (size_t)b * S_ * H_ + (size_t)split * CHUNK_ * H_;

  float m = -INFINITY, l = 0.f;
  float cx = 0.f, cy = 0.f, cz = 0.f, cw = 0.f;

  for (int i = 0; i < CHUNK_ / 8; ++i) {
    const int sl = i * 8 + w * 2;  // half 0 position; half 1 handles sl+1
    const float4 e = *reinterpret_cast<const float4*>(
        encb + (size_t)sl * H_ + lane * 4);
    float p = e.x * dv.x + e.y * dv.y + e.z * dv.z + e.w * dv.w;
    p += __shfl_xor(p, 1);
    p += __shfl_xor(p, 2);
    p += __shfl_xor(p, 4);
    p += __shfl_xor(p, 8);
    p += __shfl_xor(p, 16);      // all 32 lanes of the half now hold the score
    if (l32 == 0) s_score[sl + half] = p;
    // online softmax update (first iter: m=-inf -> corr=exp(-inf)=0, exact)
    const float mn = fmaxf(m, p);
    const float corr = __expf(m - mn);
    const float wt = __expf(p - mn);
    l = l * corr + wt;
    cx = cx * corr + wt * e.x;
    cy = cy * corr + wt * e.y;
    cz = cz * corr + wt * e.z;
    cw = cw * corr + wt * e.w;
    m = mn;
  }

  // merge the two 32-lane halves of the wave (both halves compute identically)
  const float m_o = __shfl_xor(m, 32);
  const float l_o = __shfl_xor(l, 32);
  const float cx_o = __shfl_xor(cx, 32);
  const float cy_o = __shfl_xor(cy, 32);
  const float cz_o = __shfl_xor(cz, 32);
  const float cw_o = __shfl_xor(cw, 32);
  const float M = fmaxf(m, m_o);
  const float ea = __expf(m - M);
  const float eb = __expf(m_o - M);
  if (lane == 0) { s_m[w] = M; s_l[w] = l * ea + l_o * eb; }
  if (half == 0) {
    s_ctx[w][l32 * 4 + 0] = cx * ea + cx_o * eb;
    s_ctx[w][l32 * 4 + 1] = cy * ea + cy_o * eb;
    s_ctx[w][l32 * 4 + 2] = cz * ea + cz_o * eb;
    s_ctx[w][l32 * 4 + 3] = cw * ea + cw_o * eb;
  }
  __syncthreads();

  // merge the block's 4 waves, emit one partial {m,l,ctx[128]} per block
  float* part = part_out + (size_t)blk * NPART_;
  if (t < H_) {
    const float m0 = s_m[0], m1 = s_m[1], m2 = s_m[2], m3 = s_m[3];
    const float Mb = fmaxf(fmaxf(m0, m1), fmaxf(m2, m3));
    const float e0 = __expf(m0 - Mb), e1 = __expf(m1 - Mb);
    const float e2 = __expf(m2 - Mb), e3 = __expf(m3 - Mb);
    if (t == 0) {
      part[0] = Mb;
      part[1] = s_l[0] * e0 + s_l[1] * e1 + s_l[2] * e2 + s_l[3] * e3;
    }
    part[2 + t] = s_ctx[0][t] * e0 + s_ctx[1][t] * e1 +
                  s_ctx[2][t] * e2 + s_ctx[3][t] * e3;
  }

  // coalesced raw-score write-out for this block's 512 positions
  float* so = score_out + (size_t)b * S_ + (size_t)split * CHUNK_;
  for (int j = t; j < CHUNK_; j += 256) so[j] = s_score[j];
}

// ---------------- Pass 2: merge split partials, write context, normalize attn -
__global__ __launch_bounds__(256) void s2s_attn_pass2(
    float* __restrict__ attn, float* __restrict__ ctx_out,
    const float* __restrict__ part_in) {
  const int b = blockIdx.x;
  const int t = threadIdx.x;
  const float* base = part_in + (size_t)b * SPLITS_ * NPART_;

  float mv[SPLITS_], lv[SPLITS_], ex[SPLITS_];
  float M = -INFINITY;
  for (int p = 0; p < SPLITS_; ++p) {
    mv[p] = base[p * NPART_];
    lv[p] = base[p * NPART_ + 1];
    M = fmaxf(M, mv[p]);
  }
  float L = 0.f;
  for (int p = 0; p < SPLITS_; ++p) {
    ex[p] = __expf(mv[p] - M);
    L += lv[p] * ex[p];
  }
  const float invL = 1.0f / L;

  if (t < H_) {
    float c = 0.f;
    for (int p = 0; p < SPLITS_; ++p) c += base[p * NPART_ + 2 + t] * ex[p];
    ctx_out[(size_t)b * H_ + t] = c * invL;
  }

  float* ab = attn + (size_t)b * S_;
  for (int j = t; j < S_; j += 256) ab[j] = __expf(ab[j] - M) * invL;
}

extern "C" void kernel_launch(void* const* d_in, const int* in_sizes, int n_in,
                              void* d_out, int out_size, void* d_ws, size_t ws_size,
                              hipStream_t stream) {
  const float* dec = (const float*)d_in[0];   // (128,128) fp32
  const float* enc = (const float*)d_in[1];   // (128,4096,128) fp32
  float* out = (float*)d_out;
  float* attn = out;                          // (128,4096) — scores, then probs
  float* ctx = out + (size_t)B_ * S_;         // (128,128)
  float* part = (float*)d_ws;                 // 1024 * 130 floats = 520 KiB

  s2s_attn_pass1<<<dim3(B_ * SPLITS_), dim3(256), 0, stream>>>(dec, enc, attn, part);
  s2s_attn_pass2<<<dim3(B_), dim3(256), 0, stream>>>(attn, ctx, part);
}

// Round 2
// 360.225 us; speedup vs baseline: 1.0177x; 1.0177x over previous
//
#include <hip/hip_runtime.h>
#include <math.h>

// Problem constants (fixed by setup_inputs): bs=128, seq=4096, hidden=128, fp32.
#define B_ 128
#define S_ 4096
#define H_ 128
#define SPLITS_ 16                // seq splits per batch -> 2048 blocks in pass1
#define CHUNK_ (S_ / SPLITS_)     // 256 positions per block
#define NPART_ (H_ + 2)           // per-partial: {m, l, ctx[128]}

// ---------------- Pass 1: streamed scores + online-softmax context partials ----
// Block = (batch b, split). 256 threads = 4 waves. Each wave-iteration issues
// FOUR independent 1-KiB loads (8 positions): lane half 0 owns even positions,
// half 1 odd; lane l32 owns h = l32*4..+3. The four score reductions
// (5 x __shfl_xor each, xor<32 stays inside a 32-half) are independent, so the
// DS pipe pipelines them. The online-softmax rescale (the loop-carried serial
// chain) happens ONCE per 4 positions per half instead of once per position.
// Raw scores go to the attn output region; pass 2 normalizes in place.
__global__ __launch_bounds__(256) void s2s_attn_pass1(
    const float* __restrict__ dec, const float* __restrict__ enc,
    float* __restrict__ score_out, float* __restrict__ part_out) {
  const int blk = blockIdx.x;
  const int b = blk / SPLITS_;
  const int split = blk - b * SPLITS_;
  const int t = threadIdx.x;
  const int w = t >> 6;        // wave 0..3
  const int lane = t & 63;
  const int half = lane >> 5;  // even/odd position owner
  const int l32 = lane & 31;   // h-slice owner: h = l32*4 .. +3

  __shared__ float s_score[CHUNK_];   // 1 KiB raw scores for coalesced write-out
  __shared__ float s_m[4];
  __shared__ float s_l[4];
  __shared__ float s_ctx[4][H_];      // 2 KiB per-wave context partials

  const float4 dv = *reinterpret_cast<const float4*>(dec + b * H_ + l32 * 4);
  const float* encb = enc + (size_t)b * S_ * H_ + (size_t)split * CHUNK_ * H_;

  float m = -INFINITY, l = 0.f;
  float cx = 0.f, cy = 0.f, cz = 0.f, cw = 0.f;

#pragma unroll
  for (int i = 0; i < CHUNK_ / 32; ++i) {     // 8 iterations
    const int base = i * 32 + w * 8;          // this wave's 8 positions
    // 4 independent 1-KiB wave loads; this lane's positions: base + j*2 + half
    const float4 e0 = *reinterpret_cast<const float4*>(
        encb + (size_t)(base + 0 + half) * H_ + l32 * 4);
    const float4 e1 = *reinterpret_cast<const float4*>(
        encb + (size_t)(base + 2 + half) * H_ + l32 * 4);
    const float4 e2 = *reinterpret_cast<const float4*>(
        encb + (size_t)(base + 4 + half) * H_ + l32 * 4);
    const float4 e3 = *reinterpret_cast<const float4*>(
        encb + (size_t)(base + 6 + half) * H_ + l32 * 4);

    float p0 = e0.x * dv.x + e0.y * dv.y + e0.z * dv.z + e0.w * dv.w;
    float p1 = e1.x * dv.x + e1.y * dv.y + e1.z * dv.z + e1.w * dv.w;
    float p2 = e2.x * dv.x + e2.y * dv.y + e2.z * dv.z + e2.w * dv.w;
    float p3 = e3.x * dv.x + e3.y * dv.y + e3.z * dv.z + e3.w * dv.w;
    // 20 independent shfls — pipelined through the DS unit
#pragma unroll
    for (int s = 1; s <= 16; s <<= 1) {
      p0 += __shfl_xor(p0, s);
      p1 += __shfl_xor(p1, s);
      p2 += __shfl_xor(p2, s);
      p3 += __shfl_xor(p3, s);
    }
    if (l32 == 0) {
      s_score[base + 0 + half] = p0;
      s_score[base + 2 + half] = p1;
      s_score[base + 4 + half] = p2;
      s_score[base + 6 + half] = p3;
    }
    // batched online-softmax update: one rescale per 4 positions
    const float mb = fmaxf(fmaxf(p0, p1), fmaxf(p2, p3));
    const float mn = fmaxf(m, mb);
    const float corr = __expf(m - mn);   // first iter: exp(-inf)=0, exact
    const float w0 = __expf(p0 - mn);
    const float w1 = __expf(p1 - mn);
    const float w2 = __expf(p2 - mn);
    const float w3 = __expf(p3 - mn);
    l = l * corr + (w0 + w1 + w2 + w3);
    cx = cx * corr + w0 * e0.x + w1 * e1.x + w2 * e2.x + w3 * e3.x;
    cy = cy * corr + w0 * e0.y + w1 * e1.y + w2 * e2.y + w3 * e3.y;
    cz = cz * corr + w0 * e0.z + w1 * e1.z + w2 * e2.z + w3 * e3.z;
    cw = cw * corr + w0 * e0.w + w1 * e1.w + w2 * e2.w + w3 * e3.w;
    m = mn;
  }

  // merge the two 32-lane halves of the wave (both halves hold full h-slices)
  const float m_o = __shfl_xor(m, 32);
  const float l_o = __shfl_xor(l, 32);
  const float cx_o = __shfl_xor(cx, 32);
  const float cy_o = __shfl_xor(cy, 32);
  const float cz_o = __shfl_xor(cz, 32);
  const float cw_o = __shfl_xor(cw, 32);
  const float M = fmaxf(m, m_o);
  const float ea = __expf(m - M);
  const float eb = __expf(m_o - M);
  if (lane == 0) { s_m[w] = M; s_l[w] = l * ea + l_o * eb; }
  if (half == 0) {
    s_ctx[w][l32 * 4 + 0] = cx * ea + cx_o * eb;
    s_ctx[w][l32 * 4 + 1] = cy * ea + cy_o * eb;
    s_ctx[w][l32 * 4 + 2] = cz * ea + cz_o * eb;
    s_ctx[w][l32 * 4 + 3] = cw * ea + cw_o * eb;
  }
  __syncthreads();

  // merge the block's 4 waves, emit one partial {m,l,ctx[128]} per block
  float* part = part_out + (size_t)blk * NPART_;
  if (t < H_) {
    const float m0 = s_m[0], m1 = s_m[1], m2 = s_m[2], m3 = s_m[3];
    const float Mb = fmaxf(fmaxf(m0, m1), fmaxf(m2, m3));
    const float e0 = __expf(m0 - Mb), e1 = __expf(m1 - Mb);
    const float e2 = __expf(m2 - Mb), e3 = __expf(m3 - Mb);
    if (t == 0) {
      part[0] = Mb;
      part[1] = s_l[0] * e0 + s_l[1] * e1 + s_l[2] * e2 + s_l[3] * e3;
    }
    part[2 + t] = s_ctx[0][t] * e0 + s_ctx[1][t] * e1 +
                  s_ctx[2][t] * e2 + s_ctx[3][t] * e3;
  }

  // coalesced raw-score write-out for this block's 256 positions
  float* so = score_out + (size_t)b * S_ + (size_t)split * CHUNK_;
  if (t < CHUNK_) so[t] = s_score[t];
}

// ---------------- Pass 2: merge split partials, write context, normalize attn -
__global__ __launch_bounds__(256) void s2s_attn_pass2(
    float* __restrict__ attn, float* __restrict__ ctx_out,
    const float* __restrict__ part_in) {
  const int b = blockIdx.x;
  const int t = threadIdx.x;
  const float* base = part_in + (size_t)b * SPLITS_ * NPART_;

  float mv[SPLITS_], lv[SPLITS_], ex[SPLITS_];
  float M = -INFINITY;
#pragma unroll
  for (int p = 0; p < SPLITS_; ++p) {
    mv[p] = base[p * NPART_];
    lv[p] = base[p * NPART_ + 1];
    M = fmaxf(M, mv[p]);
  }
  float L = 0.f;
#pragma unroll
  for (int p = 0; p < SPLITS_; ++p) {
    ex[p] = __expf(mv[p] - M);
    L += lv[p] * ex[p];
  }
  const float invL = 1.0f / L;

  if (t < H_) {
    float c = 0.f;
#pragma unroll
    for (int p = 0; p < SPLITS_; ++p) c += base[p * NPART_ + 2 + t] * ex[p];
    ctx_out[(size_t)b * H_ + t] = c * invL;
  }

  float* ab = attn + (size_t)b * S_;
#pragma unroll 4
  for (int j = t; j < S_; j += 256) ab[j] = __expf(ab[j] - M) * invL;
}

extern "C" void kernel_launch(void* const* d_in, const int* in_sizes, int n_in,
                              void* d_out, int out_size, void* d_ws, size_t ws_size,
                              hipStream_t stream) {
  const float* dec = (const float*)d_in[0];   // (128,128) fp32
  const float* enc = (const float*)d_in[1];   // (128,4096,128) fp32
  float* out = (float*)d_out;
  float* attn = out;                          // (128,4096) — scores, then probs
  float* ctx = out + (size_t)B_ * S_;         // (128,128)
  float* part = (float*)d_ws;                 // 2048 * 130 floats = 1.04 MiB

  s2s_attn_pass1<<<dim3(B_ * SPLITS_), dim3(256), 0, stream>>>(dec, enc, attn, part);
  s2s_attn_pass2<<<dim3(B_), dim3(256), 0, stream>>>(attn, ctx, part);
}